// Round 1
// baseline (253.420 us; speedup 1.0000x reference)
//
#include <hip/hip_runtime.h>
#include <math.h>

#define NCOL 32
#define DDIM 512
#define NPAIR 16
#define CATS 10
#define ROWS_PER_WAVE 64
#define ROW_STRIDE (NCOL * DDIM) /* 16384 floats between consecutive b rows */

// v += dpp_permuted(v). old=0 / bound_ctrl=false: lanes with no valid source
// (or masked-off rows) contribute 0.
template <int CTRL, int ROW_MASK>
__device__ __forceinline__ float dpp_add(float v) {
    int t = __builtin_amdgcn_update_dpp(0, __float_as_int(v), CTRL, ROW_MASK, 0xf, false);
    return v + __int_as_float(t);
}

// Full 64-lane sum on the VALU pipe (no LDS): result valid in lane 63.
__device__ __forceinline__ float wave_reduce_full(float v) {
    v = dpp_add<0x111, 0xf>(v);  // row_shr:1
    v = dpp_add<0x112, 0xf>(v);  // row_shr:2
    v = dpp_add<0x114, 0xf>(v);  // row_shr:4
    v = dpp_add<0x118, 0xf>(v);  // row_shr:8  -> lane15 of each row16 = row sum
    v = dpp_add<0x142, 0xa>(v);  // row_bcast:15 into rows 1,3 -> lane31=r0+r1, lane63=r2+r3
    v = dpp_add<0x143, 0xc>(v);  // row_bcast:31 into rows 2,3 -> lane63 = total
    return v;
}

// Partial: after this, lane31 = sum(lanes 0..31), lane63 = sum(lanes 32..63).
__device__ __forceinline__ float wave_reduce_halves(float v) {
    v = dpp_add<0x111, 0xf>(v);
    v = dpp_add<0x112, 0xf>(v);
    v = dpp_add<0x114, 0xf>(v);
    v = dpp_add<0x118, 0xf>(v);
    v = dpp_add<0x142, 0xa>(v);  // row_bcast:15 -> lane31, lane63 hold half-sums
    return v;
}

__global__ __launch_bounds__(256, 4) void fused_cols_kernel(
    const float* __restrict__ x,
    const float* __restrict__ Wn,
    const float* __restrict__ bn,
    const float* __restrict__ Wc,
    const float* __restrict__ bc,
    float* __restrict__ out)
{
    const int lane  = threadIdx.x & 63;
    const int wslot = threadIdx.x >> 6;
    const int typ   = blockIdx.x & 1;   // 0 = numeric cols, 1 = categorical cols
    const int tb    = blockIdx.x >> 1;  // 0..511 per type
    // wave id 0..2047 per type; force SGPR so weight/bias addressing is scalar
    const int wid   = __builtin_amdgcn_readfirstlane(tb * 4 + wslot);
    const int p     = wid & (NPAIR - 1);
    const int chunk = wid >> 4;                       // 0..127
    const size_t b0 = (size_t)chunk * ROWS_PER_WAVE;  // first row of this wave

    if (typ == 0) {
        // ---------------- numeric: out[b, 2p] = tanh(x[b,2p,:] . Wn[p] + bn[p])
        float w[8];
        {
            float4 wa = *(const float4*)(Wn + p * DDIM + lane * 4);
            float4 wb = *(const float4*)(Wn + p * DDIM + 256 + lane * 4);
            w[0]=wa.x; w[1]=wa.y; w[2]=wa.z; w[3]=wa.w;
            w[4]=wb.x; w[5]=wb.y; w[6]=wb.z; w[7]=wb.w;
        }
        const float bias = bn[p];
        const float* xb = x + b0 * ROW_STRIDE + (size_t)(2 * p) * DDIM;
        float* ob = out + b0 * NCOL + 2 * p;

        float4 a0 = *(const float4*)(xb + lane * 4);
        float4 a1 = *(const float4*)(xb + 256 + lane * 4);
        #pragma unroll 2
        for (int i = 0; i < ROWS_PER_WAVE; ++i) {
            const int nx = (i + 1 < ROWS_PER_WAVE) ? (i + 1) : i;
            const float* xn = xb + (size_t)nx * ROW_STRIDE;
            float4 n0 = *(const float4*)(xn + lane * 4);
            float4 n1 = *(const float4*)(xn + 256 + lane * 4);

            float s = a0.x * w[0];
            s = fmaf(a0.y, w[1], s);
            s = fmaf(a0.z, w[2], s);
            s = fmaf(a0.w, w[3], s);
            s = fmaf(a1.x, w[4], s);
            s = fmaf(a1.y, w[5], s);
            s = fmaf(a1.z, w[6], s);
            s = fmaf(a1.w, w[7], s);
            s = wave_reduce_full(s);
            if (lane == 63) ob[(size_t)i * NCOL] = tanhf(s + bias);
            a0 = n0; a1 = n1;
        }
    } else {
        // ---------------- categorical: out[b, 2p+1] = argmax_c(x[b,2p+1,:] . Wc[p,:,c] + bc[p,c])
        // Per-lane weight slice: d in {4*lane..4*lane+3} u {256+4*lane..+3}
        float wc[80];  // wc[j*10+c] (j=0..3 low half), wc[40+j*10+c] (high half)
        {
            const float* w0 = Wc + ((size_t)p * DDIM + lane * 4) * CATS;
            const float* w1 = Wc + ((size_t)p * DDIM + 256 + lane * 4) * CATS;
            #pragma unroll
            for (int k = 0; k < 10; ++k) {
                float4 t = *(const float4*)(w0 + k * 4);
                wc[4*k] = t.x; wc[4*k+1] = t.y; wc[4*k+2] = t.z; wc[4*k+3] = t.w;
            }
            #pragma unroll
            for (int k = 0; k < 10; ++k) {
                float4 t = *(const float4*)(w1 + k * 4);
                wc[40+4*k] = t.x; wc[40+4*k+1] = t.y; wc[40+4*k+2] = t.z; wc[40+4*k+3] = t.w;
            }
        }
        float biasf[CATS];
        #pragma unroll
        for (int c = 0; c < CATS; ++c) biasf[c] = bc[p * CATS + c];

        const float* xb = x + b0 * ROW_STRIDE + (size_t)(2 * p + 1) * DDIM;
        float* ob = out + b0 * NCOL + 2 * p + 1;

        float4 a0 = *(const float4*)(xb + lane * 4);
        float4 a1 = *(const float4*)(xb + 256 + lane * 4);
        #pragma unroll 2
        for (int i = 0; i < ROWS_PER_WAVE; ++i) {
            const int nx = (i + 1 < ROWS_PER_WAVE) ? (i + 1) : i;
            const float* xn = xb + (size_t)nx * ROW_STRIDE;
            float4 n0 = *(const float4*)(xn + lane * 4);
            float4 n1 = *(const float4*)(xn + 256 + lane * 4);

            double best = -1.0e300;
            int bi = 0;
            #pragma unroll
            for (int c = 0; c < CATS; ++c) {
                float s = a0.x * wc[c];
                s = fmaf(a0.y, wc[10 + c], s);
                s = fmaf(a0.z, wc[20 + c], s);
                s = fmaf(a0.w, wc[30 + c], s);
                s = fmaf(a1.x, wc[40 + c], s);
                s = fmaf(a1.y, wc[50 + c], s);
                s = fmaf(a1.z, wc[60 + c], s);
                s = fmaf(a1.w, wc[70 + c], s);
                s = wave_reduce_halves(s);          // lane31/lane63 = half sums
                double d = (double)s;
                d += __shfl_xor(d, 32);             // f64 final combine (tie insurance)
                d += (double)biasf[c];
                if (d > best) { best = d; bi = c; } // strict '>' => first-max, np semantics
            }
            if (lane == 63) ob[(size_t)i * NCOL] = (float)bi;
            a0 = n0; a1 = n1;
        }
    }
}

extern "C" void kernel_launch(void* const* d_in, const int* in_sizes, int n_in,
                              void* d_out, int out_size, void* d_ws, size_t ws_size,
                              hipStream_t stream) {
    const float* x  = (const float*)d_in[0];
    const float* Wn = (const float*)d_in[1];
    const float* bn = (const float*)d_in[2];
    const float* Wc = (const float*)d_in[3];
    const float* bc = (const float*)d_in[4];
    float* out = (float*)d_out;

    dim3 grid(1024);   // even blocks: numeric, odd blocks: categorical
    dim3 block(256);
    hipLaunchKernelGGL(fused_cols_kernel, grid, block, 0, stream,
                       x, Wn, bn, Wc, bc, out);
}

// Round 2
// 128.667 us; speedup vs baseline: 1.9696x; 1.9696x over previous
//
#include <hip/hip_runtime.h>
#include <math.h>

#define NCOL 32
#define DDIM 512
#define NPAIR 16
#define CATS 10
#define ROWS_PER_WAVE 64
#define ROW_STRIDE (NCOL * DDIM) /* 16384 floats between consecutive b rows */

// v += dpp_permuted(v). old=0 / bound_ctrl=false: masked-off rows contribute 0.
template <int CTRL, int ROW_MASK>
__device__ __forceinline__ float dpp_add(float v) {
    int t = __builtin_amdgcn_update_dpp(0, __float_as_int(v), CTRL, ROW_MASK, 0xf, false);
    return v + __int_as_float(t);
}
// pure DPP move (no add): returns permuted value (0 in masked-off rows).
template <int CTRL, int ROW_MASK>
__device__ __forceinline__ float dpp_mov(float v) {
    int t = __builtin_amdgcn_update_dpp(0, __float_as_int(v), CTRL, ROW_MASK, 0xf, false);
    return __int_as_float(t);
}

// After this: lane31 = sum(lanes 0..31), lane63 = sum(lanes 32..63). VALU only.
__device__ __forceinline__ float wave_reduce_halves(float v) {
    v = dpp_add<0x111, 0xf>(v);  // row_shr:1
    v = dpp_add<0x112, 0xf>(v);  // row_shr:2
    v = dpp_add<0x114, 0xf>(v);  // row_shr:4
    v = dpp_add<0x118, 0xf>(v);  // row_shr:8  -> lane15 of each row16 = row sum
    v = dpp_add<0x142, 0xa>(v);  // row_bcast:15 -> lane31, lane63 hold half-sums
    return v;
}
// Full 64-lane sum, valid in lane 63.
__device__ __forceinline__ float wave_reduce_full(float v) {
    v = wave_reduce_halves(v);
    v = dpp_add<0x143, 0xc>(v);  // row_bcast:31 into rows 2,3 -> lane63 = total
    return v;
}

__device__ __forceinline__ float dot8(const float4& a0, const float4& a1,
                                      const float* w, int stride) {
    float s = a0.x * w[0 * stride];
    s = fmaf(a0.y, w[1 * stride], s);
    s = fmaf(a0.z, w[2 * stride], s);
    s = fmaf(a0.w, w[3 * stride], s);
    s = fmaf(a1.x, w[4 * stride], s);
    s = fmaf(a1.y, w[5 * stride], s);
    s = fmaf(a1.z, w[6 * stride], s);
    s = fmaf(a1.w, w[7 * stride], s);
    return s;
}

__device__ __forceinline__ void num_row(const float4& a0, const float4& a1,
                                        const float w[8], float bias,
                                        int lane, float* dst) {
    float s = dot8(a0, a1, w, 1);
    s = wave_reduce_full(s);
    if (lane == 63) *dst = tanhf(s + bias);
}

__device__ __forceinline__ void cat_row(const float4& a0, const float4& a1,
                                        const float (&wc)[80],
                                        const double (&biasd)[CATS],
                                        int lane, float* dst) {
    double best = -1.0e300;
    int bi = 0;
    #pragma unroll
    for (int c = 0; c < CATS; ++c) {
        float s = a0.x * wc[c];
        s = fmaf(a0.y, wc[10 + c], s);
        s = fmaf(a0.z, wc[20 + c], s);
        s = fmaf(a0.w, wc[30 + c], s);
        s = fmaf(a1.x, wc[40 + c], s);
        s = fmaf(a1.y, wc[50 + c], s);
        s = fmaf(a1.z, wc[60 + c], s);
        s = fmaf(a1.w, wc[70 + c], s);
        s = wave_reduce_halves(s);            // lane31 = lo-half, lane63 = hi-half
        float slo = dpp_mov<0x143, 0xc>(s);   // lane63 <- lane31 (VALU, no LDS)
        double d = (double)s + (double)slo + biasd[c];  // same math as passing ver.
        if (d > best) { best = d; bi = c; }   // strict '>' => first-max (np)
    }
    if (lane == 63) *dst = (float)bi;
}

__global__ __launch_bounds__(256, 3) void fused_cols_kernel(
    const float* __restrict__ x,
    const float* __restrict__ Wn,
    const float* __restrict__ bn,
    const float* __restrict__ Wc,
    const float* __restrict__ bc,
    float* __restrict__ out)
{
    const int lane  = threadIdx.x & 63;
    const int wslot = threadIdx.x >> 6;
    const int typ   = blockIdx.x & 1;   // 0 = numeric cols, 1 = categorical cols
    const int tb    = blockIdx.x >> 1;  // 0..511 per type
    const int wid   = __builtin_amdgcn_readfirstlane(tb * 4 + wslot);
    const int p     = wid & (NPAIR - 1);
    const int chunk = wid >> 4;                       // 0..127
    const size_t b0 = (size_t)chunk * ROWS_PER_WAVE;  // first row of this wave

    if (typ == 0) {
        // ---- numeric: out[b, 2p] = tanh(x[b,2p,:] . Wn[p] + bn[p])
        float w[8];
        {
            float4 wa = *(const float4*)(Wn + p * DDIM + lane * 4);
            float4 wb = *(const float4*)(Wn + p * DDIM + 256 + lane * 4);
            w[0]=wa.x; w[1]=wa.y; w[2]=wa.z; w[3]=wa.w;
            w[4]=wb.x; w[5]=wb.y; w[6]=wb.z; w[7]=wb.w;
        }
        const float bias = __int_as_float(
            __builtin_amdgcn_readfirstlane(__float_as_int(bn[p])));
        const float* xb = x + b0 * ROW_STRIDE + (size_t)(2 * p) * DDIM;
        float* ob = out + b0 * NCOL + 2 * p;

        // 2-deep prefetch, named buffers only (no runtime-indexed arrays)
        float4 A0 = *(const float4*)(xb + lane * 4);
        float4 A1 = *(const float4*)(xb + 256 + lane * 4);
        float4 B0 = *(const float4*)(xb + ROW_STRIDE + lane * 4);
        float4 B1 = *(const float4*)(xb + ROW_STRIDE + 256 + lane * 4);
        for (int i = 0; i < ROWS_PER_WAVE; i += 2) {
            const int r2 = (i + 2 < ROWS_PER_WAVE) ? i + 2 : ROWS_PER_WAVE - 1;
            const int r3 = (i + 3 < ROWS_PER_WAVE) ? i + 3 : ROWS_PER_WAVE - 1;
            const float* x2 = xb + (size_t)r2 * ROW_STRIDE;
            const float* x3 = xb + (size_t)r3 * ROW_STRIDE;
            float4 C0 = *(const float4*)(x2 + lane * 4);
            float4 C1 = *(const float4*)(x2 + 256 + lane * 4);
            num_row(A0, A1, w, bias, lane, ob + (size_t)i * NCOL);
            float4 D0 = *(const float4*)(x3 + lane * 4);
            float4 D1 = *(const float4*)(x3 + 256 + lane * 4);
            num_row(B0, B1, w, bias, lane, ob + (size_t)(i + 1) * NCOL);
            A0 = C0; A1 = C1; B0 = D0; B1 = D1;
        }
    } else {
        // ---- categorical: out[b, 2p+1] = argmax_c(x[b,2p+1,:] . Wc[p,:,c] + bc[p,c])
        float wc[80];  // wc[dd*10+c] low half (d=4*lane+dd), wc[40+dd*10+c] high half
        {
            const float* w0 = Wc + ((size_t)p * DDIM + lane * 4) * CATS;
            const float* w1 = Wc + ((size_t)p * DDIM + 256 + lane * 4) * CATS;
            #pragma unroll
            for (int k = 0; k < 10; ++k) {
                float4 t = *(const float4*)(w0 + k * 4);
                wc[4*k] = t.x; wc[4*k+1] = t.y; wc[4*k+2] = t.z; wc[4*k+3] = t.w;
            }
            #pragma unroll
            for (int k = 0; k < 10; ++k) {
                float4 t = *(const float4*)(w1 + k * 4);
                wc[40+4*k] = t.x; wc[40+4*k+1] = t.y; wc[40+4*k+2] = t.z; wc[40+4*k+3] = t.w;
            }
        }
        double biasd[CATS];  // wave-uniform -> SGPR pairs
        #pragma unroll
        for (int c = 0; c < CATS; ++c)
            biasd[c] = (double)__int_as_float(
                __builtin_amdgcn_readfirstlane(__float_as_int(bc[p * CATS + c])));

        const float* xb = x + b0 * ROW_STRIDE + (size_t)(2 * p + 1) * DDIM;
        float* ob = out + b0 * NCOL + 2 * p + 1;

        float4 A0 = *(const float4*)(xb + lane * 4);
        float4 A1 = *(const float4*)(xb + 256 + lane * 4);
        float4 B0 = *(const float4*)(xb + ROW_STRIDE + lane * 4);
        float4 B1 = *(const float4*)(xb + ROW_STRIDE + 256 + lane * 4);
        for (int i = 0; i < ROWS_PER_WAVE; i += 2) {
            const int r2 = (i + 2 < ROWS_PER_WAVE) ? i + 2 : ROWS_PER_WAVE - 1;
            const int r3 = (i + 3 < ROWS_PER_WAVE) ? i + 3 : ROWS_PER_WAVE - 1;
            const float* x2 = xb + (size_t)r2 * ROW_STRIDE;
            const float* x3 = xb + (size_t)r3 * ROW_STRIDE;
            float4 C0 = *(const float4*)(x2 + lane * 4);
            float4 C1 = *(const float4*)(x2 + 256 + lane * 4);
            cat_row(A0, A1, wc, biasd, lane, ob + (size_t)i * NCOL);
            float4 D0 = *(const float4*)(x3 + lane * 4);
            float4 D1 = *(const float4*)(x3 + 256 + lane * 4);
            cat_row(B0, B1, wc, biasd, lane, ob + (size_t)(i + 1) * NCOL);
            A0 = C0; A1 = C1; B0 = D0; B1 = D1;
        }
    }
}

extern "C" void kernel_launch(void* const* d_in, const int* in_sizes, int n_in,
                              void* d_out, int out_size, void* d_ws, size_t ws_size,
                              hipStream_t stream) {
    const float* x  = (const float*)d_in[0];
    const float* Wn = (const float*)d_in[1];
    const float* bn = (const float*)d_in[2];
    const float* Wc = (const float*)d_in[3];
    const float* bc = (const float*)d_in[4];
    float* out = (float*)d_out;

    dim3 grid(1024);   // even blocks: numeric, odd blocks: categorical
    dim3 block(256);
    hipLaunchKernelGGL(fused_cols_kernel, grid, block, 0, stream,
                       x, Wn, bn, Wc, bc, out);
}